// Round 6
// baseline (276.773 us; speedup 1.0000x reference)
//
#include <hip/hip_runtime.h>
#include <hip/hip_bf16.h>
#include <hip/hip_fp8.h>

#define N0 100000
#define N1 50000
#define N2 20000
#define DD 128
#define E0 600000
#define E1 300000

#define NSEG_TOT (2 * N1 + 2 * N2)              // 140000 concat CSR segments
#define ETOT     (2 * E0 + 2 * E1)              // 1800000 edges

// counting-sort geometry
#define SEG_SHIFT 9                              // 512 segments per bucket
#define NBK  ((NSEG_TOT + 511) / 512)            // 274 buckets
#define CH   2048                                // edges per chunk
#define NCH  ((ETOT + CH - 1) / CH)              // 879 chunks
#define PADCAP 8192                              // eidx slots per bucket (mean 6582, +20 sigma)

#define CAST_BLOCKS 6250                         // N0*DD/8 / 256
#define PREP_BLOCKS 48                           // 2*6144/256
#define PROLOGUE_BLOCKS (CAST_BLOCKS + PREP_BLOCKS + NCH)

typedef __attribute__((ext_vector_type(8))) short short8;   // 8 bf16 (4 VGPRs)
typedef __attribute__((ext_vector_type(4))) float floatx4;  // MFMA acc
typedef __attribute__((ext_vector_type(2))) float floatx2;  // cvt_pk result

__device__ __forceinline__ void st2bf(__hip_bfloat16* p, float a, float b) {
    __hip_bfloat162 v;
    v.x = __float2bfloat16(a);
    v.y = __float2bfloat16(b);
    *(__hip_bfloat162*)p = v;
}
__device__ __forceinline__ short bf16bits(float v) {
    __hip_bfloat16 b = __float2bfloat16(v);
    return *(short*)&b;
}
__device__ __forceinline__ float bf2f(unsigned short u) {
    return __uint_as_float(((unsigned int)u) << 16);
}
__device__ __forceinline__ float4 ld4bf(const __hip_bfloat16* p) {  // 8B load
    ushort4 u = *(const ushort4*)p;
    return make_float4(bf2f(u.x), bf2f(u.y), bf2f(u.z), bf2f(u.w));
}
__device__ __forceinline__ void st4bf(__hip_bfloat16* p, float4 v) { // 8B store
    short vs[4];
    vs[0] = bf16bits(v.x); vs[1] = bf16bits(v.y);
    vs[2] = bf16bits(v.z); vs[3] = bf16bits(v.w);
    *(int2*)p = *(int2*)vs;
}

// --- HW fp8 (OCP e4m3) conversion: v_cvt_pk_fp8_f32 / v_cvt_pk_f32_fp8 ---
__device__ __forceinline__ unsigned f8enc4(float x, float y, float z, float w) {
    int v = 0;
    v = __builtin_amdgcn_cvt_pk_fp8_f32(x, y, v, false);   // bytes 0,1
    v = __builtin_amdgcn_cvt_pk_fp8_f32(z, w, v, true);    // bytes 2,3
    return (unsigned)v;
}
// decode 8 fp8 and accumulate with a mask-scale (fma keeps loads hoistable)
__device__ __forceinline__ void f8acc8m(unsigned lo, unsigned hi, float m, float* acc) {
    floatx2 p0 = __builtin_amdgcn_cvt_pk_f32_fp8((int)lo, false);
    floatx2 p1 = __builtin_amdgcn_cvt_pk_f32_fp8((int)lo, true);
    floatx2 p2 = __builtin_amdgcn_cvt_pk_f32_fp8((int)hi, false);
    floatx2 p3 = __builtin_amdgcn_cvt_pk_f32_fp8((int)hi, true);
    acc[0] = fmaf(m, p0[0], acc[0]); acc[1] = fmaf(m, p0[1], acc[1]);
    acc[2] = fmaf(m, p1[0], acc[2]); acc[3] = fmaf(m, p1[1], acc[3]);
    acc[4] = fmaf(m, p2[0], acc[4]); acc[5] = fmaf(m, p2[1], acc[5]);
    acc[6] = fmaf(m, p3[0], acc[6]); acc[7] = fmaf(m, p3[1], acc[7]);
}

// inclusive Hillis-Steele scan over 256 threads; every thread must call.
__device__ __forceinline__ int scan256(int s, int* sh, int t) {
    sh[t] = s;
    __syncthreads();
    for (int off = 1; off < 256; off <<= 1) {
        int tmp = (t >= off) ? sh[t - off] : 0;
        __syncthreads();
        sh[t] += tmp;
        __syncthreads();
    }
    return sh[t];
}

// Edge mapping for the concatenated CSR (4 edge lists)
__device__ __forceinline__ int2 edge_seg_src(int e,
    const int* s0, const int* d0, const int* s1, const int* d1,
    const int* s2, const int* d2, const int* s3, const int* d3)
{
    if (e < E0)               return make_int2(s0[e],            d0[e]);
    if (e < 2 * E0)           return make_int2(s1[e - E0],       N1 + d1[e - E0]);
    if (e < 2 * E0 + E1)      return make_int2(s2[e - 2 * E0],   2 * N1 + d2[e - 2 * E0]);
    int ee = e - 2 * E0 - E1;
    return make_int2(s3[ee], 2 * N1 + N2 + d3[ee]);
}

// ---------------------------------------------------------------------------
// Prologue: [cast | weight-prep | chunk-local bucket sort], by blockIdx range.
// ---------------------------------------------------------------------------
__global__ __launch_bounds__(256) void prologue_kernel(
    const float* __restrict__ x, __hip_bfloat16* __restrict__ xb,
    unsigned char* __restrict__ xf8,
    const int* __restrict__ s0a, const int* __restrict__ d0a,
    const int* __restrict__ s0b, const int* __restrict__ d0b,
    const int* __restrict__ s1a, const int* __restrict__ d1a,
    const int* __restrict__ s1b, const int* __restrict__ d1b,
    int* __restrict__ cntmat, int* __restrict__ ofsmat,
    unsigned* __restrict__ chunkbuf,
    const float* __restrict__ Ws1a, const float* __restrict__ Ws1b,
    const float* __restrict__ Wn1a, const float* __restrict__ Wn1b,
    const float* __restrict__ Ws2a, const float* __restrict__ Ws2b,
    const float* __restrict__ Wn2a, const float* __restrict__ Wn2b,
    short* __restrict__ wfrag1, short* __restrict__ wfrag2)
{
    __shared__ int hist[512];
    __shared__ int ofs[512];
    __shared__ int sh[256];
    __shared__ unsigned rec[CH];
    const int bid = blockIdx.x;
    const int t = threadIdx.x;

    if (bid < CAST_BLOCKS) {
        int i = bid * 256 + t;                          // 8-elem group, < 1.6M exactly
        const float4* xp = (const float4*)x + (size_t)i * 2;
        float4 a = xp[0], b = xp[1];
        __hip_bfloat16* pb = xb + (size_t)i * 8;
        st2bf(pb + 0, a.x, a.y); st2bf(pb + 2, a.z, a.w);
        st2bf(pb + 4, b.x, b.y); st2bf(pb + 6, b.z, b.w);
        uint2 w8;
        w8.x = f8enc4(a.x, a.y, a.z, a.w);
        w8.y = f8enc4(b.x, b.y, b.z, b.w);
        *(uint2*)(xf8 + (size_t)i * 8) = w8;
    } else if (bid < CAST_BLOCKS + PREP_BLOCKS) {
        int p = (bid - CAST_BLOCKS) * 256 + t;          // < 12288
        int layer = p >= 6144;
        int q = p - layer * 6144;
        int lane = q & 63;
        int mt = (q >> 6) & 7;
        int kc = q >> 9;
        int n = mt * 16 + (lane & 15);
        int k0 = kc * 32 + ((lane >> 4) << 3);
        const float* Wsa = layer ? Ws2a : Ws1a;
        const float* Wsb = layer ? Ws2b : Ws1b;
        const float* Wna = layer ? Wn2a : Wn1a;
        const float* Wnb = layer ? Wn2b : Wn1b;
        short* wf = layer ? wfrag2 : wfrag1;
        short vals[8];
#pragma unroll
        for (int j = 0; j < 8; j++) {
            int k = k0 + j;
            float w;
            if (k < 128)      w = Wsa[k * DD + n] + Wsb[k * DD + n];
            else if (k < 256) w = Wna[(k - 128) * DD + n];
            else              w = Wnb[(k - 256) * DD + n];
            vals[j] = bf16bits(w);
        }
        *(short8*)(wf + (size_t)q * 8) = *(short8*)vals;
    } else {
        const int chunk = bid - CAST_BLOCKS - PREP_BLOCKS;
        const int ebase = chunk * CH;
        const int ecount = (ETOT - ebase < CH) ? (ETOT - ebase) : CH;

        hist[t] = 0; hist[t + 256] = 0;
        __syncthreads();

        int2 myrec[CH / 256];
#pragma unroll
        for (int it = 0; it < CH / 256; it++) {
            int e = ebase + it * 256 + t;
            int2 r = make_int2(0, -1);
            if (e < ETOT) {
                r = edge_seg_src(e, s0a, d0a, s0b, d0b, s1a, d1a, s1b, d1b);
                atomicAdd(&hist[r.y >> SEG_SHIFT], 1);   // LDS atomic
            }
            myrec[it] = r;
        }
        __syncthreads();

        // exclusive scan over 512 bucket slots (2/thread)
        const int l0 = 2 * t, l1 = 2 * t + 1;
        int c0 = hist[l0], c1 = hist[l1];
        int s = c0 + c1;
        int incl = scan256(s, sh, t);
        int ex = incl - s;
        ofs[l0] = ex;
        ofs[l1] = ex + c0;
        __syncthreads();

        // write per-chunk counts and offsets (before cursors mutate ofs)
        for (int g = t; g < NBK; g += 256) {
            cntmat[(size_t)g * NCH + chunk] = hist[g];
            ofsmat[(size_t)g * NCH + chunk] = ofs[g];
        }
        __syncthreads();

        // scatter packed records into bucket order in LDS (ofs now cursors)
#pragma unroll
        for (int it = 0; it < CH / 256; it++) {
            int2 r = myrec[it];
            if (r.y >= 0) {
                int rk = atomicAdd(&ofs[r.y >> SEG_SHIFT], 1);  // LDS atomic
                rec[rk] = (unsigned)r.x | ((unsigned)(r.y & 511) << 17);
            }
        }
        __syncthreads();

        for (int i = t; i < ecount; i += 256)
            chunkbuf[ebase + i] = rec[i];
    }
}

// ---------------------------------------------------------------------------
// Finalize: block g scans its OWN cntmat row, gathers chunk slices into LDS,
// LDS hist+scan -> row_beg/cnt, scatters srcs into padded eidx region.
// ---------------------------------------------------------------------------
__global__ __launch_bounds__(256) void csr_finalize_kernel(
    const unsigned* __restrict__ chunkbuf,
    const int* __restrict__ cntmat, const int* __restrict__ ofsmat,
    int* __restrict__ row_beg, int* __restrict__ row_cnt,
    int* __restrict__ eidx)
{
    __shared__ int sh[256];
    __shared__ int preL[NCH];
    __shared__ int lenL[NCH];
    __shared__ int cnt[512];
    __shared__ int excl[512];
    __shared__ unsigned rec[PADCAP];
    const int t = threadIdx.x;
    const int g = blockIdx.x;
    const int l0 = 2 * t, l1 = 2 * t + 1;

    // 1. scan own cntmat row -> preL (exclusive), lenL
    int v[4]; int s = 0;
#pragma unroll
    for (int i = 0; i < 4; i++) {
        int idx = t * 4 + i;
        v[i] = (idx < NCH) ? cntmat[(size_t)g * NCH + idx] : 0;
        s += v[i];
    }
    int incl = scan256(s, sh, t);
    int ex = incl - s;
#pragma unroll
    for (int i = 0; i < 4; i++) {
        int idx = t * 4 + i;
        if (idx < NCH) { preL[idx] = ex; lenL[idx] = v[i]; }
        ex += v[i];
    }
    int Eloc = sh[255];
    if (Eloc > PADCAP) Eloc = PADCAP;     // statistically impossible; safety clamp
    cnt[l0] = 0; cnt[l1] = 0;
    __syncthreads();

    // 2. gather slices into rec at scan positions (no atomics)
    for (int c = t; c < NCH; c += 256) {
        int len = lenL[c];
        int dst = preL[c];
        int off = ofsmat[(size_t)g * NCH + c];
        const unsigned* src = chunkbuf + (size_t)c * CH + off;
        for (int i = 0; i < len; i++) rec[dst + i] = src[i];
    }
    __syncthreads();

    // 3. per-segment hist
    for (int i = t; i < Eloc; i += 256)
        atomicAdd(&cnt[rec[i] >> 17], 1);                 // LDS atomic
    __syncthreads();

    // 4. scan 512 segment counts -> excl
    int c0 = cnt[l0], c1 = cnt[l1];
    int ssum = c0 + c1;
    int inc2 = scan256(ssum, sh, t);
    int ex2 = inc2 - ssum;
    excl[l0] = ex2;
    excl[l1] = ex2 + c0;
    __syncthreads();

    // 5. write row_beg / row_cnt, then reset cnt as cursors
    const int segbase = g << SEG_SHIFT;
    const int base = g * PADCAP;
    int nloc = NSEG_TOT - segbase;
    if (nloc > 512) nloc = 512;
    for (int l = t; l < nloc; l += 256) {
        row_beg[segbase + l] = base + excl[l];
        row_cnt[segbase + l] = cnt[l];
    }
    __syncthreads();
    cnt[l0] = 0; cnt[l1] = 0;
    __syncthreads();

    // 6. scatter srcs into padded eidx region
    for (int i = t; i < Eloc; i += 256) {
        unsigned r = rec[i];
        int l = r >> 17;
        int pos = atomicAdd(&cnt[l], 1);
        eidx[base + excl[l] + pos] = (int)(r & 0x1FFFF);
    }
}

// ---------------------------------------------------------------------------
// Layer-1 aggregation (fp8 table), 2 segments per wave: two independent
// dependency chains (eidx -> 4 row loads each) issued back-to-back before any
// decode -> 8 gather loads in flight per wave. Guards are wave-uniform.
// Quarter-waves: 16 lanes x 8 B = one 128-B row; 4 rows per load instruction.
// Store: lanes 0..15 write segment A's row, lanes 16..31 write segment B's.
// ---------------------------------------------------------------------------
__global__ __launch_bounds__(256) void aggregate_fp8_kernel(
    const unsigned char* __restrict__ xf8,
    const int* __restrict__ row_beg, const int* __restrict__ row_cnt,
    const int* __restrict__ eidx,
    __hip_bfloat16* __restrict__ hn,
    int npair)
{
    int w = (blockIdx.x * 256 + threadIdx.x) >> 6;
    const int lane = threadIdx.x & 63;
    if (w >= npair) return;
    w = __builtin_amdgcn_readfirstlane(w);
    const int sA = 2 * w, sB = 2 * w + 1;

    const int begA = row_beg[sA];
    const int cntA = row_cnt[sA];
    const int endA = begA + cntA;
    const int begB = row_beg[sB];
    const int cntB = row_cnt[sB];
    const int endB = begB + cntB;

    const int q = lane >> 4;
    const int l16 = lane & 15;

    float accA[8], accB[8];
#pragma unroll
    for (int j = 0; j < 8; j++) { accA[j] = 0.f; accB[j] = 0.f; }

    int kbA = begA, kbB = begB;
    while (kbA < endA || kbB < endB) {
        const bool hA = kbA < endA;
        const bool hB = kbB < endB;
        uint2 vA[4], vB[4];
        float mA[4], mB[4];
        if (hA) {
            int nA = endA - kbA; if (nA > 16) nA = 16;
            int myi = eidx[kbA + (l16 < nA ? l16 : nA - 1)];
#pragma unroll
            for (int j = 0; j < 4; j++) {
                int r = q + 4 * j;
                int sl = r < nA ? r : nA - 1;
                int ri = __shfl(myi, sl);
                vA[j] = *(const uint2*)(xf8 + (size_t)ri * DD + l16 * 8);
                mA[j] = (r < nA) ? 1.f : 0.f;
            }
        }
        if (hB) {
            int nB = endB - kbB; if (nB > 16) nB = 16;
            int myi = eidx[kbB + (l16 < nB ? l16 : nB - 1)];
#pragma unroll
            for (int j = 0; j < 4; j++) {
                int r = q + 4 * j;
                int sl = r < nB ? r : nB - 1;
                int ri = __shfl(myi, sl);
                vB[j] = *(const uint2*)(xf8 + (size_t)ri * DD + l16 * 8);
                mB[j] = (r < nB) ? 1.f : 0.f;
            }
        }
        if (hA) {
#pragma unroll
            for (int j = 0; j < 4; j++) f8acc8m(vA[j].x, vA[j].y, mA[j], accA);
            kbA += 16;
        }
        if (hB) {
#pragma unroll
            for (int j = 0; j < 4; j++) f8acc8m(vB[j].x, vB[j].y, mB[j], accB);
            kbB += 16;
        }
    }

#pragma unroll
    for (int j = 0; j < 8; j++) {
        accA[j] += __shfl_xor(accA[j], 16);
        accA[j] += __shfl_xor(accA[j], 32);
        accB[j] += __shfl_xor(accB[j], 16);
        accB[j] += __shfl_xor(accB[j], 32);
    }

    if (lane < 16) {
        const float inv = 1.f / (float)(cntA > 1 ? cntA : 1);
        short vs[8];
#pragma unroll
        for (int j = 0; j < 8; j++) vs[j] = bf16bits(accA[j] * inv);
        *(int4*)(hn + (size_t)sA * DD + l16 * 8) = *(int4*)vs;
    } else if (lane < 32) {
        const float inv = 1.f / (float)(cntB > 1 ? cntB : 1);
        short vs[8];
#pragma unroll
        for (int j = 0; j < 8; j++) vs[j] = bf16bits(accB[j] * inv);
        *(int4*)(hn + (size_t)sB * DD + l16 * 8) = *(int4*)vs;
    }
}

// ---------------------------------------------------------------------------
// Layer-2 aggregation (bf16 table), 2 segments per wave, same MLP scheme.
// Half-waves: 32 lanes x 8 B = one 256-B row; 2 rows per load instruction.
// ---------------------------------------------------------------------------
__global__ __launch_bounds__(256) void aggregate_kernel(
    const __hip_bfloat16* __restrict__ xb,
    const int* __restrict__ row_beg, const int* __restrict__ row_cnt,
    const int* __restrict__ eidx,
    __hip_bfloat16* __restrict__ hn,
    int npair)
{
    int w = (blockIdx.x * 256 + threadIdx.x) >> 6;
    const int lane = threadIdx.x & 63;
    if (w >= npair) return;
    w = __builtin_amdgcn_readfirstlane(w);
    const int sA = 2 * w, sB = 2 * w + 1;

    const int begA = row_beg[sA];
    const int cntA = row_cnt[sA];
    const int endA = begA + cntA;
    const int begB = row_beg[sB];
    const int cntB = row_cnt[sB];
    const int endB = begB + cntB;

    const int half = lane >> 5;
    const int l32 = lane & 31;

    float4 sa = make_float4(0.f, 0.f, 0.f, 0.f);
    float4 sb = make_float4(0.f, 0.f, 0.f, 0.f);

    int kbA = begA, kbB = begB;
    while (kbA < endA || kbB < endB) {
        const bool hA = kbA < endA;
        const bool hB = kbB < endB;
        ushort4 vA[8], vB[8];
        float mA[8], mB[8];
        if (hA) {
            int nA = endA - kbA; if (nA > 16) nA = 16;
            int myi = eidx[kbA + (l32 < nA ? l32 : nA - 1)];
#pragma unroll
            for (int j = 0; j < 8; j++) {
                int r = half + 2 * j;
                int sl = r < nA ? r : nA - 1;
                int ri = __shfl(myi, sl);
                vA[j] = *(const ushort4*)(xb + (long)ri * DD + l32 * 4);
                mA[j] = (r < nA) ? 1.f : 0.f;
            }
        }
        if (hB) {
            int nB = endB - kbB; if (nB > 16) nB = 16;
            int myi = eidx[kbB + (l32 < nB ? l32 : nB - 1)];
#pragma unroll
            for (int j = 0; j < 8; j++) {
                int r = half + 2 * j;
                int sl = r < nB ? r : nB - 1;
                int ri = __shfl(myi, sl);
                vB[j] = *(const ushort4*)(xb + (long)ri * DD + l32 * 4);
                mB[j] = (r < nB) ? 1.f : 0.f;
            }
        }
        if (hA) {
#pragma unroll
            for (int j = 0; j < 8; j++) {
                sa.x = fmaf(mA[j], bf2f(vA[j].x), sa.x);
                sa.y = fmaf(mA[j], bf2f(vA[j].y), sa.y);
                sa.z = fmaf(mA[j], bf2f(vA[j].z), sa.z);
                sa.w = fmaf(mA[j], bf2f(vA[j].w), sa.w);
            }
            kbA += 16;
        }
        if (hB) {
#pragma unroll
            for (int j = 0; j < 8; j++) {
                sb.x = fmaf(mB[j], bf2f(vB[j].x), sb.x);
                sb.y = fmaf(mB[j], bf2f(vB[j].y), sb.y);
                sb.z = fmaf(mB[j], bf2f(vB[j].z), sb.z);
                sb.w = fmaf(mB[j], bf2f(vB[j].w), sb.w);
            }
            kbB += 16;
        }
    }

    sa.x += __shfl_xor(sa.x, 32);
    sa.y += __shfl_xor(sa.y, 32);
    sa.z += __shfl_xor(sa.z, 32);
    sa.w += __shfl_xor(sa.w, 32);
    sb.x += __shfl_xor(sb.x, 32);
    sb.y += __shfl_xor(sb.y, 32);
    sb.z += __shfl_xor(sb.z, 32);
    sb.w += __shfl_xor(sb.w, 32);

    if (!half) {
        const float inv = 1.f / (float)(cntA > 1 ? cntA : 1);
        float4 m = make_float4(sa.x * inv, sa.y * inv, sa.z * inv, sa.w * inv);
        st4bf(hn + (long)sA * DD + l32 * 4, m);
    } else {
        const float inv = 1.f / (float)(cntB > 1 ? cntB : 1);
        float4 m = make_float4(sb.x * inv, sb.y * inv, sb.z * inv, sb.w * inv);
        st4bf(hn + (long)sB * DD + l32 * 4, m);
    }
}

// ---------------------------------------------------------------------------
// MFMA combine: D[outcol][node] = Wc^T (A-op) x Xcat^T (B-op), K=384.
// ---------------------------------------------------------------------------
template <bool RELU, typename TOUT>
__global__ __launch_bounds__(256) void mfma_combine_kernel(
    const __hip_bfloat16* __restrict__ xself,   // [M][128] bf16
    const __hip_bfloat16* __restrict__ hn,      // [2*M][128] bf16
    const short* __restrict__ wfrag,            // 12*8*64*8 bf16 bits
    const float* __restrict__ b0, const float* __restrict__ b1,
    TOUT* __restrict__ out, int M)
{
    const int t = threadIdx.x;
    const int wave = t >> 6;
    const int lane = t & 63;
    const int nsub = lane & 15;
    const int quad = lane >> 4;
    const int base = blockIdx.x * 128 + wave * 32;

    const int node0 = base + nsub;
    const int node1 = base + 16 + nsub;
    const long n0c = node0 < M ? node0 : M - 1;
    const long n1c = node1 < M ? node1 : M - 1;

    floatx4 acc[2][8];
#pragma unroll
    for (int nt = 0; nt < 2; nt++)
#pragma unroll
        for (int mt = 0; mt < 8; mt++) acc[nt][mt] = (floatx4){0.f, 0.f, 0.f, 0.f};

    for (int kc = 0; kc < 12; kc++) {
        const __hip_bfloat16* src;
        long r0, r1;
        int koff;
        if (kc < 4)      { src = xself; koff = kc * 32;       r0 = n0c;     r1 = n1c; }
        else if (kc < 8) { src = hn;    koff = (kc - 4) * 32; r0 = n0c;     r1 = n1c; }
        else             { src = hn;    koff = (kc - 8) * 32; r0 = M + n0c; r1 = M + n1c; }

        short8 bf0 = *(const short8*)(src + r0 * DD + koff + quad * 8);
        short8 bf1 = *(const short8*)(src + r1 * DD + koff + quad * 8);
        const short* wbase = wfrag + ((size_t)(kc * 8) * 64 + lane) * 8;
#pragma unroll
        for (int mt = 0; mt < 8; mt++) {
            short8 af = *(const short8*)(wbase + (size_t)mt * 64 * 8);
            acc[0][mt] = __builtin_amdgcn_mfma_f32_16x16x32_bf16(af, bf0, acc[0][mt], 0, 0, 0);
            acc[1][mt] = __builtin_amdgcn_mfma_f32_16x16x32_bf16(af, bf1, acc[1][mt], 0, 0, 0);
        }
    }

#pragma unroll
    for (int nt = 0; nt < 2; nt++) {
        int node = (nt == 0) ? node0 : node1;
        if (node >= M) continue;
#pragma unroll
        for (int mt = 0; mt < 8; mt++) {
            int c0 = mt * 16 + quad * 4;
            float4 bb0 = *(const float4*)(b0 + c0);
            float4 bb1 = *(const float4*)(b1 + c0);
            float v0 = acc[nt][mt][0] + bb0.x + bb1.x;
            float v1 = acc[nt][mt][1] + bb0.y + bb1.y;
            float v2 = acc[nt][mt][2] + bb0.z + bb1.z;
            float v3 = acc[nt][mt][3] + bb0.w + bb1.w;
            if (RELU) {
                v0 = v0 > 0.f ? v0 : 0.f;
                v1 = v1 > 0.f ? v1 : 0.f;
                v2 = v2 > 0.f ? v2 : 0.f;
                v3 = v3 > 0.f ? v3 : 0.f;
            }
            TOUT* p = out + (long)node * DD + c0;
            if constexpr (sizeof(TOUT) == 4) {
                *(float4*)p = make_float4(v0, v1, v2, v3);
            } else {
                short vs[4];
                vs[0] = bf16bits(v0); vs[1] = bf16bits(v1);
                vs[2] = bf16bits(v2); vs[3] = bf16bits(v3);
                *(int2*)p = *(int2*)vs;
            }
        }
    }
}

// ---------------------------------------------------------------------------

extern "C" void kernel_launch(void* const* d_in, const int* in_sizes, int n_in,
                              void* d_out, int out_size, void* d_ws, size_t ws_size,
                              hipStream_t stream)
{
    const float* x = (const float*)d_in[0];
    const int* e0_src_r0 = (const int*)d_in[1];
    const int* e0_dst_r0 = (const int*)d_in[2];
    const int* e0_src_r1 = (const int*)d_in[3];
    const int* e0_dst_r1 = (const int*)d_in[4];
    const int* e1_src_r0 = (const int*)d_in[5];
    const int* e1_dst_r0 = (const int*)d_in[6];
    const int* e1_src_r1 = (const int*)d_in[7];
    const int* e1_dst_r1 = (const int*)d_in[8];
    const float* Ws1_r0 = (const float*)d_in[9];
    const float* Wn1_r0 = (const float*)d_in[10];
    const float* Ws1_r1 = (const float*)d_in[11];
    const float* Wn1_r1 = (const float*)d_in[12];
    const float* Ws2_r0 = (const float*)d_in[13];
    const float* Wn2_r0 = (const float*)d_in[14];
    const float* Ws2_r1 = (const float*)d_in[15];
    const float* Wn2_r1 = (const float*)d_in[16];
    const float* b1_r0 = (const float*)d_in[17];
    const float* b1_r1 = (const float*)d_in[18];
    const float* b2_r0 = (const float*)d_in[19];
    const float* b2_r1 = (const float*)d_in[20];
    float* out = (float*)d_out;

    __hip_bfloat16* xb = (__hip_bfloat16*)d_ws;
    __hip_bfloat16* h1 = xb;
    unsigned char* xf8 = (unsigned char*)(xb + (size_t)N0 * DD);
    __hip_bfloat16* hn = (__hip_bfloat16*)(xf8 + (size_t)N0 * DD);
    unsigned* chunkbuf = (unsigned*)hn;
    int* eidx     = (int*)(hn + (size_t)2 * N1 * DD);
    int* row_beg  = eidx + NBK * PADCAP;
    int* row_cnt  = row_beg + NSEG_TOT;
    int* cntmat   = row_cnt + NSEG_TOT;
    int* ofsmat   = cntmat + NBK * NCH;
    short* wfrag1 = (short*)(ofsmat + NBK * NCH);
    short* wfrag2 = wfrag1 + 12 * 8 * 64 * 8;

    // 1. prologue: cast (bf16 + fp8) + weight-prep + chunk-local bucket sort
    prologue_kernel<<<PROLOGUE_BLOCKS, 256, 0, stream>>>(
        x, xb, xf8,
        e0_src_r0, e0_dst_r0, e0_src_r1, e0_dst_r1,
        e1_src_r0, e1_dst_r0, e1_src_r1, e1_dst_r1,
        cntmat, ofsmat, chunkbuf,
        Ws1_r0, Ws1_r1, Wn1_r0, Wn1_r1,
        Ws2_r0, Ws2_r1, Wn2_r0, Wn2_r1,
        wfrag1, wfrag2);

    // 2. per-bucket finalize (own-row scan -> gather -> row_beg/cnt + eidx)
    csr_finalize_kernel<<<NBK, 256, 0, stream>>>(
        chunkbuf, cntmat, ofsmat, row_beg, row_cnt, eidx);

    // 3-4. layer 1 (npair = N1 pairs of segments, 4 waves/block)
    aggregate_fp8_kernel<<<(N1 + 3) / 4, 256, 0, stream>>>(
        xf8, row_beg, row_cnt, eidx, hn, N1);
    mfma_combine_kernel<true, __hip_bfloat16>
        <<<(N1 + 127) / 128, 256, 0, stream>>>(xb, hn, wfrag1, b1_r0, b1_r1, h1, N1);

    // 5-6. layer 2 (npair = N2 pairs)
    aggregate_kernel<<<(N2 + 3) / 4, 256, 0, stream>>>(
        h1, row_beg + 2 * N1, row_cnt + 2 * N1, eidx, hn, N2);
    mfma_combine_kernel<false, float>
        <<<(N2 + 127) / 128, 256, 0, stream>>>(h1, hn, wfrag2, b2_r0, b2_r1, out, N2);
}

// Round 8
// 270.691 us; speedup vs baseline: 1.0225x; 1.0225x over previous
//
#include <hip/hip_runtime.h>
#include <hip/hip_bf16.h>
#include <hip/hip_fp8.h>

#define N0 100000
#define N1 50000
#define N2 20000
#define DD 128
#define E0 600000
#define E1 300000

#define NSEG_TOT (2 * N1 + 2 * N2)              // 140000 concat CSR segments
#define ETOT     (2 * E0 + 2 * E1)              // 1800000 edges

// counting-sort geometry
#define SEG_SHIFT 9                              // 512 segments per bucket
#define NBK  ((NSEG_TOT + 511) / 512)            // 274 buckets
#define CH   2048                                // edges per chunk
#define NCH  ((ETOT + CH - 1) / CH)              // 879 chunks
#define PADCAP 8192                              // eidx slots per bucket (mean 6582, +20 sigma)

#define CAST_BLOCKS 6250                         // N0*DD/8 / 256
#define PREP_BLOCKS 48                           // 2*6144/256
#define PROLOGUE_BLOCKS (CAST_BLOCKS + PREP_BLOCKS + NCH)

typedef __attribute__((ext_vector_type(8))) short short8;   // 8 bf16 (4 VGPRs)
typedef __attribute__((ext_vector_type(4))) float floatx4;  // MFMA acc
typedef __attribute__((ext_vector_type(2))) float floatx2;  // cvt_pk result
typedef __attribute__((ext_vector_type(2))) int intx2;      // NT-store payload (8B)
typedef __attribute__((ext_vector_type(4))) int intx4;      // NT-store payload (16B)

__device__ __forceinline__ void st2bf(__hip_bfloat16* p, float a, float b) {
    __hip_bfloat162 v;
    v.x = __float2bfloat16(a);
    v.y = __float2bfloat16(b);
    *(__hip_bfloat162*)p = v;
}
__device__ __forceinline__ short bf16bits(float v) {
    __hip_bfloat16 b = __float2bfloat16(v);
    return *(short*)&b;
}
__device__ __forceinline__ float bf2f(unsigned short u) {
    return __uint_as_float(((unsigned int)u) << 16);
}
__device__ __forceinline__ float4 ld4bf(const __hip_bfloat16* p) {  // 8B load
    ushort4 u = *(const ushort4*)p;
    return make_float4(bf2f(u.x), bf2f(u.y), bf2f(u.z), bf2f(u.w));
}
__device__ __forceinline__ void st4bf(__hip_bfloat16* p, float4 v) { // 8B store
    short vs[4];
    vs[0] = bf16bits(v.x); vs[1] = bf16bits(v.y);
    vs[2] = bf16bits(v.z); vs[3] = bf16bits(v.w);
    *(int2*)p = *(int2*)vs;
}
// nontemporal variant: streamed output, don't pollute L2 (table wants residency)
__device__ __forceinline__ void st4bf_nt(__hip_bfloat16* p, float4 v) {
    short vs[4];
    vs[0] = bf16bits(v.x); vs[1] = bf16bits(v.y);
    vs[2] = bf16bits(v.z); vs[3] = bf16bits(v.w);
    __builtin_nontemporal_store(*(intx2*)vs, (intx2*)p);
}

// --- HW fp8 (OCP e4m3) conversion: v_cvt_pk_fp8_f32 / v_cvt_pk_f32_fp8 ---
__device__ __forceinline__ unsigned f8enc4(float x, float y, float z, float w) {
    int v = 0;
    v = __builtin_amdgcn_cvt_pk_fp8_f32(x, y, v, false);   // bytes 0,1
    v = __builtin_amdgcn_cvt_pk_fp8_f32(z, w, v, true);    // bytes 2,3
    return (unsigned)v;
}
// decode 8 fp8 and accumulate with a mask-scale (fma keeps loads hoistable)
__device__ __forceinline__ void f8acc8m(unsigned lo, unsigned hi, float m, float* acc) {
    floatx2 p0 = __builtin_amdgcn_cvt_pk_f32_fp8((int)lo, false);
    floatx2 p1 = __builtin_amdgcn_cvt_pk_f32_fp8((int)lo, true);
    floatx2 p2 = __builtin_amdgcn_cvt_pk_f32_fp8((int)hi, false);
    floatx2 p3 = __builtin_amdgcn_cvt_pk_f32_fp8((int)hi, true);
    acc[0] = fmaf(m, p0[0], acc[0]); acc[1] = fmaf(m, p0[1], acc[1]);
    acc[2] = fmaf(m, p1[0], acc[2]); acc[3] = fmaf(m, p1[1], acc[3]);
    acc[4] = fmaf(m, p2[0], acc[4]); acc[5] = fmaf(m, p2[1], acc[5]);
    acc[6] = fmaf(m, p3[0], acc[6]); acc[7] = fmaf(m, p3[1], acc[7]);
}

// inclusive Hillis-Steele scan over 256 threads; every thread must call.
__device__ __forceinline__ int scan256(int s, int* sh, int t) {
    sh[t] = s;
    __syncthreads();
    for (int off = 1; off < 256; off <<= 1) {
        int tmp = (t >= off) ? sh[t - off] : 0;
        __syncthreads();
        sh[t] += tmp;
        __syncthreads();
    }
    return sh[t];
}

// Edge mapping for the concatenated CSR (4 edge lists)
__device__ __forceinline__ int2 edge_seg_src(int e,
    const int* s0, const int* d0, const int* s1, const int* d1,
    const int* s2, const int* d2, const int* s3, const int* d3)
{
    if (e < E0)               return make_int2(s0[e],            d0[e]);
    if (e < 2 * E0)           return make_int2(s1[e - E0],       N1 + d1[e - E0]);
    if (e < 2 * E0 + E1)      return make_int2(s2[e - 2 * E0],   2 * N1 + d2[e - 2 * E0]);
    int ee = e - 2 * E0 - E1;
    return make_int2(s3[ee], 2 * N1 + N2 + d3[ee]);
}

// ---------------------------------------------------------------------------
// Prologue: [cast | weight-prep | chunk-local bucket sort], by blockIdx range.
// ---------------------------------------------------------------------------
__global__ __launch_bounds__(256) void prologue_kernel(
    const float* __restrict__ x, __hip_bfloat16* __restrict__ xb,
    unsigned char* __restrict__ xf8,
    const int* __restrict__ s0a, const int* __restrict__ d0a,
    const int* __restrict__ s0b, const int* __restrict__ d0b,
    const int* __restrict__ s1a, const int* __restrict__ d1a,
    const int* __restrict__ s1b, const int* __restrict__ d1b,
    int* __restrict__ cntmat, int* __restrict__ ofsmat,
    unsigned* __restrict__ chunkbuf,
    const float* __restrict__ Ws1a, const float* __restrict__ Ws1b,
    const float* __restrict__ Wn1a, const float* __restrict__ Wn1b,
    const float* __restrict__ Ws2a, const float* __restrict__ Ws2b,
    const float* __restrict__ Wn2a, const float* __restrict__ Wn2b,
    short* __restrict__ wfrag1, short* __restrict__ wfrag2)
{
    __shared__ int hist[512];
    __shared__ int ofs[512];
    __shared__ int sh[256];
    __shared__ unsigned rec[CH];
    const int bid = blockIdx.x;
    const int t = threadIdx.x;

    if (bid < CAST_BLOCKS) {
        int i = bid * 256 + t;                          // 8-elem group, < 1.6M exactly
        const float4* xp = (const float4*)x + (size_t)i * 2;
        float4 a = xp[0], b = xp[1];
        __hip_bfloat16* pb = xb + (size_t)i * 8;
        st2bf(pb + 0, a.x, a.y); st2bf(pb + 2, a.z, a.w);
        st2bf(pb + 4, b.x, b.y); st2bf(pb + 6, b.z, b.w);
        uint2 w8;
        w8.x = f8enc4(a.x, a.y, a.z, a.w);
        w8.y = f8enc4(b.x, b.y, b.z, b.w);
        *(uint2*)(xf8 + (size_t)i * 8) = w8;
    } else if (bid < CAST_BLOCKS + PREP_BLOCKS) {
        int p = (bid - CAST_BLOCKS) * 256 + t;          // < 12288
        int layer = p >= 6144;
        int q = p - layer * 6144;
        int lane = q & 63;
        int mt = (q >> 6) & 7;
        int kc = q >> 9;
        int n = mt * 16 + (lane & 15);
        int k0 = kc * 32 + ((lane >> 4) << 3);
        const float* Wsa = layer ? Ws2a : Ws1a;
        const float* Wsb = layer ? Ws2b : Ws1b;
        const float* Wna = layer ? Wn2a : Wn1a;
        const float* Wnb = layer ? Wn2b : Wn1b;
        short* wf = layer ? wfrag2 : wfrag1;
        short vals[8];
#pragma unroll
        for (int j = 0; j < 8; j++) {
            int k = k0 + j;
            float w;
            if (k < 128)      w = Wsa[k * DD + n] + Wsb[k * DD + n];
            else if (k < 256) w = Wna[(k - 128) * DD + n];
            else              w = Wnb[(k - 256) * DD + n];
            vals[j] = bf16bits(w);
        }
        *(short8*)(wf + (size_t)q * 8) = *(short8*)vals;
    } else {
        const int chunk = bid - CAST_BLOCKS - PREP_BLOCKS;
        const int ebase = chunk * CH;
        const int ecount = (ETOT - ebase < CH) ? (ETOT - ebase) : CH;

        hist[t] = 0; hist[t + 256] = 0;
        __syncthreads();

        int2 myrec[CH / 256];
#pragma unroll
        for (int it = 0; it < CH / 256; it++) {
            int e = ebase + it * 256 + t;
            int2 r = make_int2(0, -1);
            if (e < ETOT) {
                r = edge_seg_src(e, s0a, d0a, s0b, d0b, s1a, d1a, s1b, d1b);
                atomicAdd(&hist[r.y >> SEG_SHIFT], 1);   // LDS atomic
            }
            myrec[it] = r;
        }
        __syncthreads();

        // exclusive scan over 512 bucket slots (2/thread)
        const int l0 = 2 * t, l1 = 2 * t + 1;
        int c0 = hist[l0], c1 = hist[l1];
        int s = c0 + c1;
        int incl = scan256(s, sh, t);
        int ex = incl - s;
        ofs[l0] = ex;
        ofs[l1] = ex + c0;
        __syncthreads();

        // write per-chunk counts and offsets (before cursors mutate ofs)
        for (int g = t; g < NBK; g += 256) {
            cntmat[(size_t)g * NCH + chunk] = hist[g];
            ofsmat[(size_t)g * NCH + chunk] = ofs[g];
        }
        __syncthreads();

        // scatter packed records into bucket order in LDS (ofs now cursors)
#pragma unroll
        for (int it = 0; it < CH / 256; it++) {
            int2 r = myrec[it];
            if (r.y >= 0) {
                int rk = atomicAdd(&ofs[r.y >> SEG_SHIFT], 1);  // LDS atomic
                rec[rk] = (unsigned)r.x | ((unsigned)(r.y & 511) << 17);
            }
        }
        __syncthreads();

        for (int i = t; i < ecount; i += 256)
            chunkbuf[ebase + i] = rec[i];
    }
}

// ---------------------------------------------------------------------------
// Finalize: block g scans its OWN cntmat row, gathers chunk slices into LDS,
// LDS hist+scan -> row_beg/cnt, scatters srcs into padded eidx region.
// ---------------------------------------------------------------------------
__global__ __launch_bounds__(256) void csr_finalize_kernel(
    const unsigned* __restrict__ chunkbuf,
    const int* __restrict__ cntmat, const int* __restrict__ ofsmat,
    int* __restrict__ row_beg, int* __restrict__ row_cnt,
    int* __restrict__ eidx)
{
    __shared__ int sh[256];
    __shared__ int preL[NCH];
    __shared__ int lenL[NCH];
    __shared__ int cnt[512];
    __shared__ int excl[512];
    __shared__ unsigned rec[PADCAP];
    const int t = threadIdx.x;
    const int g = blockIdx.x;
    const int l0 = 2 * t, l1 = 2 * t + 1;

    // 1. scan own cntmat row -> preL (exclusive), lenL
    int v[4]; int s = 0;
#pragma unroll
    for (int i = 0; i < 4; i++) {
        int idx = t * 4 + i;
        v[i] = (idx < NCH) ? cntmat[(size_t)g * NCH + idx] : 0;
        s += v[i];
    }
    int incl = scan256(s, sh, t);
    int ex = incl - s;
#pragma unroll
    for (int i = 0; i < 4; i++) {
        int idx = t * 4 + i;
        if (idx < NCH) { preL[idx] = ex; lenL[idx] = v[i]; }
        ex += v[i];
    }
    int Eloc = sh[255];
    if (Eloc > PADCAP) Eloc = PADCAP;     // statistically impossible; safety clamp
    cnt[l0] = 0; cnt[l1] = 0;
    __syncthreads();

    // 2. gather slices into rec at scan positions (no atomics)
    for (int c = t; c < NCH; c += 256) {
        int len = lenL[c];
        int dst = preL[c];
        int off = ofsmat[(size_t)g * NCH + c];
        const unsigned* src = chunkbuf + (size_t)c * CH + off;
        for (int i = 0; i < len; i++) rec[dst + i] = src[i];
    }
    __syncthreads();

    // 3. per-segment hist
    for (int i = t; i < Eloc; i += 256)
        atomicAdd(&cnt[rec[i] >> 17], 1);                 // LDS atomic
    __syncthreads();

    // 4. scan 512 segment counts -> excl
    int c0 = cnt[l0], c1 = cnt[l1];
    int ssum = c0 + c1;
    int inc2 = scan256(ssum, sh, t);
    int ex2 = inc2 - ssum;
    excl[l0] = ex2;
    excl[l1] = ex2 + c0;
    __syncthreads();

    // 5. write row_beg / row_cnt, then reset cnt as cursors
    const int segbase = g << SEG_SHIFT;
    const int base = g * PADCAP;
    int nloc = NSEG_TOT - segbase;
    if (nloc > 512) nloc = 512;
    for (int l = t; l < nloc; l += 256) {
        row_beg[segbase + l] = base + excl[l];
        row_cnt[segbase + l] = cnt[l];
    }
    __syncthreads();
    cnt[l0] = 0; cnt[l1] = 0;
    __syncthreads();

    // 6. scatter srcs into padded eidx region
    for (int i = t; i < Eloc; i += 256) {
        unsigned r = rec[i];
        int l = r >> 17;
        int pos = atomicAdd(&cnt[l], 1);
        eidx[base + excl[l] + pos] = (int)(r & 0x1FFFF);
    }
}

// ---------------------------------------------------------------------------
// Layer-1 aggregation (fp8 table), R5 structure: per 16-row chunk, ONE
// coalesced eidx load (NT: streamed once, keep L2 for the table), shfl
// broadcast, 4 row loads per lane in flight, mask-fma accumulate.
// Quarter-waves: 16 lanes x 8 B = one 128-B row.
// ---------------------------------------------------------------------------
__global__ __launch_bounds__(256) void aggregate_fp8_kernel(
    const unsigned char* __restrict__ xf8,
    const int* __restrict__ row_beg, const int* __restrict__ row_cnt,
    const int* __restrict__ eidx,
    __hip_bfloat16* __restrict__ hn,
    int nseg)
{
    int wid = (blockIdx.x * 256 + threadIdx.x) >> 6;
    const int lane = threadIdx.x & 63;
    if (wid >= nseg) return;
    wid = __builtin_amdgcn_readfirstlane(wid);

    const int beg = row_beg[wid];
    const int cnt = row_cnt[wid];
    const int end = beg + cnt;
    const int q = lane >> 4;
    const int l16 = lane & 15;

    float acc[8];
#pragma unroll
    for (int j = 0; j < 8; j++) acc[j] = 0.f;

    for (int kb = beg; kb < end; kb += 16) {
        int nrows = end - kb;
        if (nrows > 16) nrows = 16;
        // one coalesced NT load of the chunk's indices (streamed once)
        int myidx = __builtin_nontemporal_load(eidx + kb + (l16 < nrows ? l16 : nrows - 1));
        uint2 vv[4];
        float mm[4];
#pragma unroll
        for (int j = 0; j < 4; j++) {
            int r = q + 4 * j;
            int sl = r < nrows ? r : nrows - 1;      // clamped slot
            int ri = __shfl(myidx, sl);              // broadcast, no mem
            vv[j] = *(const uint2*)(xf8 + (size_t)ri * DD + l16 * 8);
            mm[j] = (r < nrows) ? 1.f : 0.f;
        }
#pragma unroll
        for (int j = 0; j < 4; j++)
            f8acc8m(vv[j].x, vv[j].y, mm[j], acc);
    }

#pragma unroll
    for (int j = 0; j < 8; j++) {
        acc[j] += __shfl_xor(acc[j], 16);
        acc[j] += __shfl_xor(acc[j], 32);
    }

    if (lane < 16) {
        const float inv = 1.f / (float)(cnt > 1 ? cnt : 1);
        short vs[8];
#pragma unroll
        for (int j = 0; j < 8; j++) vs[j] = bf16bits(acc[j] * inv);
        // NT store: hn not re-read until combine1; don't evict table lines
        __builtin_nontemporal_store(*(intx4*)vs, (intx4*)(hn + (size_t)wid * DD + l16 * 8));
    }
}

// ---------------------------------------------------------------------------
// Layer-2 aggregation (bf16 table), R5 structure + NT on eidx/hn streams.
// Half-waves: 32 lanes x 8 B; 8 row loads per lane in flight.
// ---------------------------------------------------------------------------
__global__ __launch_bounds__(256) void aggregate_kernel(
    const __hip_bfloat16* __restrict__ xb,
    const int* __restrict__ row_beg, const int* __restrict__ row_cnt,
    const int* __restrict__ eidx,
    __hip_bfloat16* __restrict__ hn,
    int nseg)
{
    int wid = (blockIdx.x * 256 + threadIdx.x) >> 6;
    const int lane = threadIdx.x & 63;
    if (wid >= nseg) return;
    wid = __builtin_amdgcn_readfirstlane(wid);

    const int beg = row_beg[wid];
    const int cnt = row_cnt[wid];
    const int end = beg + cnt;
    const int half = lane >> 5;
    const int l32 = lane & 31;

    float4 s = make_float4(0.f, 0.f, 0.f, 0.f);
    for (int kb = beg; kb < end; kb += 16) {
        int nrows = end - kb;
        if (nrows > 16) nrows = 16;
        int myidx = __builtin_nontemporal_load(eidx + kb + (l32 < nrows ? l32 : nrows - 1));
        ushort4 vv[8];
        float mm[8];
#pragma unroll
        for (int j = 0; j < 8; j++) {
            int r = half + 2 * j;
            int sl = r < nrows ? r : nrows - 1;
            int ri = __shfl(myidx, sl);
            vv[j] = *(const ushort4*)(xb + (long)ri * DD + l32 * 4);
            mm[j] = (r < nrows) ? 1.f : 0.f;
        }
#pragma unroll
        for (int j = 0; j < 8; j++) {
            s.x = fmaf(mm[j], bf2f(vv[j].x), s.x);
            s.y = fmaf(mm[j], bf2f(vv[j].y), s.y);
            s.z = fmaf(mm[j], bf2f(vv[j].z), s.z);
            s.w = fmaf(mm[j], bf2f(vv[j].w), s.w);
        }
    }

    s.x += __shfl_xor(s.x, 32);
    s.y += __shfl_xor(s.y, 32);
    s.z += __shfl_xor(s.z, 32);
    s.w += __shfl_xor(s.w, 32);

    if (!half) {
        const float inv = 1.f / (float)(cnt > 1 ? cnt : 1);
        float4 m = make_float4(s.x * inv, s.y * inv, s.z * inv, s.w * inv);
        st4bf_nt(hn + (long)wid * DD + l32 * 4, m);
    }
}

// ---------------------------------------------------------------------------
// MFMA combine: D[outcol][node] = Wc^T (A-op) x Xcat^T (B-op), K=384.
// ---------------------------------------------------------------------------
template <bool RELU, typename TOUT>
__global__ __launch_bounds__(256) void mfma_combine_kernel(
    const __hip_bfloat16* __restrict__ xself,   // [M][128] bf16
    const __hip_bfloat16* __restrict__ hn,      // [2*M][128] bf16
    const short* __restrict__ wfrag,            // 12*8*64*8 bf16 bits
    const float* __restrict__ b0, const float* __restrict__ b1,
    TOUT* __restrict__ out, int M)
{
    const int t = threadIdx.x;
    const int wave = t >> 6;
    const int lane = t & 63;
    const int nsub = lane & 15;
    const int quad = lane >> 4;
    const int base = blockIdx.x * 128 + wave * 32;

    const int node0 = base + nsub;
    const int node1 = base + 16 + nsub;
    const long n0c = node0 < M ? node0 : M - 1;
    const long n1c = node1 < M ? node1 : M - 1;

    floatx4 acc[2][8];
#pragma unroll
    for (int nt = 0; nt < 2; nt++)
#pragma unroll
        for (int mt = 0; mt < 8; mt++) acc[nt][mt] = (floatx4){0.f, 0.f, 0.f, 0.f};

    for (int kc = 0; kc < 12; kc++) {
        const __hip_bfloat16* src;
        long r0, r1;
        int koff;
        if (kc < 4)      { src = xself; koff = kc * 32;       r0 = n0c;     r1 = n1c; }
        else if (kc < 8) { src = hn;    koff = (kc - 4) * 32; r0 = n0c;     r1 = n1c; }
        else             { src = hn;    koff = (kc - 8) * 32; r0 = M + n0c; r1 = M + n1c; }

        short8 bf0 = *(const short8*)(src + r0 * DD + koff + quad * 8);
        short8 bf1 = *(const short8*)(src + r1 * DD + koff + quad * 8);
        const short* wbase = wfrag + ((size_t)(kc * 8) * 64 + lane) * 8;
#pragma unroll
        for (int mt = 0; mt < 8; mt++) {
            short8 af = *(const short8*)(wbase + (size_t)mt * 64 * 8);
            acc[0][mt] = __builtin_amdgcn_mfma_f32_16x16x32_bf16(af, bf0, acc[0][mt], 0, 0, 0);
            acc[1][mt] = __builtin_amdgcn_mfma_f32_16x16x32_bf16(af, bf1, acc[1][mt], 0, 0, 0);
        }
    }

#pragma unroll
    for (int nt = 0; nt < 2; nt++) {
        int node = (nt == 0) ? node0 : node1;
        if (node >= M) continue;
#pragma unroll
        for (int mt = 0; mt < 8; mt++) {
            int c0 = mt * 16 + quad * 4;
            float4 bb0 = *(const float4*)(b0 + c0);
            float4 bb1 = *(const float4*)(b1 + c0);
            float v0 = acc[nt][mt][0] + bb0.x + bb1.x;
            float v1 = acc[nt][mt][1] + bb0.y + bb1.y;
            float v2 = acc[nt][mt][2] + bb0.z + bb1.z;
            float v3 = acc[nt][mt][3] + bb0.w + bb1.w;
            if (RELU) {
                v0 = v0 > 0.f ? v0 : 0.f;
                v1 = v1 > 0.f ? v1 : 0.f;
                v2 = v2 > 0.f ? v2 : 0.f;
                v3 = v3 > 0.f ? v3 : 0.f;
            }
            TOUT* p = out + (long)node * DD + c0;
            if constexpr (sizeof(TOUT) == 4) {
                *(float4*)p = make_float4(v0, v1, v2, v3);
            } else {
                short vs[4];
                vs[0] = bf16bits(v0); vs[1] = bf16bits(v1);
                vs[2] = bf16bits(v2); vs[3] = bf16bits(v3);
                *(int2*)p = *(int2*)vs;
            }
        }
    }
}

// ---------------------------------------------------------------------------

extern "C" void kernel_launch(void* const* d_in, const int* in_sizes, int n_in,
                              void* d_out, int out_size, void* d_ws, size_t ws_size,
                              hipStream_t stream)
{
    const float* x = (const float*)d_in[0];
    const int* e0_src_r0 = (const int*)d_in[1];
    const int* e0_dst_r0 = (const int*)d_in[2];
    const int* e0_src_r1 = (const int*)d_in[3];
    const int* e0_dst_r1 = (const int*)d_in[4];
    const int* e1_src_r0 = (const int*)d_in[5];
    const int* e1_dst_r0 = (const int*)d_in[6];
    const int* e1_src_r1 = (const int*)d_in[7];
    const int* e1_dst_r1 = (const int*)d_in[8];
    const float* Ws1_r0 = (const float*)d_in[9];
    const float* Wn1_r0 = (const float*)d_in[10];
    const float* Ws1_r1 = (const float*)d_in[11];
    const float* Wn1_r1 = (const float*)d_in[12];
    const float* Ws2_r0 = (const float*)d_in[13];
    const float* Wn2_r0 = (const float*)d_in[14];
    const float* Ws2_r1 = (const float*)d_in[15];
    const float* Wn2_r1 = (const float*)d_in[16];
    const float* b1_r0 = (const float*)d_in[17];
    const float* b1_r1 = (const float*)d_in[18];
    const float* b2_r0 = (const float*)d_in[19];
    const float* b2_r1 = (const float*)d_in[20];
    float* out = (float*)d_out;

    __hip_bfloat16* xb = (__hip_bfloat16*)d_ws;
    __hip_bfloat16* h1 = xb;
    unsigned char* xf8 = (unsigned char*)(xb + (size_t)N0 * DD);
    __hip_bfloat16* hn = (__hip_bfloat16*)(xf8 + (size_t)N0 * DD);
    unsigned* chunkbuf = (unsigned*)hn;
    int* eidx     = (int*)(hn + (size_t)2 * N1 * DD);
    int* row_beg  = eidx + NBK * PADCAP;
    int* row_cnt  = row_beg + NSEG_TOT;
    int* cntmat   = row_cnt + NSEG_TOT;
    int* ofsmat   = cntmat + NBK * NCH;
    short* wfrag1 = (short*)(ofsmat + NBK * NCH);
    short* wfrag2 = wfrag1 + 12 * 8 * 64 * 8;

    // 1. prologue: cast (bf16 + fp8) + weight-prep + chunk-local bucket sort
    prologue_kernel<<<PROLOGUE_BLOCKS, 256, 0, stream>>>(
        x, xb, xf8,
        e0_src_r0, e0_dst_r0, e0_src_r1, e0_dst_r1,
        e1_src_r0, e1_dst_r0, e1_src_r1, e1_dst_r1,
        cntmat, ofsmat, chunkbuf,
        Ws1_r0, Ws1_r1, Wn1_r0, Wn1_r1,
        Ws2_r0, Ws2_r1, Wn2_r0, Wn2_r1,
        wfrag1, wfrag2);

    // 2. per-bucket finalize (own-row scan -> gather -> row_beg/cnt + eidx)
    csr_finalize_kernel<<<NBK, 256, 0, stream>>>(
        chunkbuf, cntmat, ofsmat, row_beg, row_cnt, eidx);

    // 3-4. layer 1
    aggregate_fp8_kernel<<<(2 * N1 + 3) / 4, 256, 0, stream>>>(
        xf8, row_beg, row_cnt, eidx, hn, 2 * N1);
    mfma_combine_kernel<true, __hip_bfloat16>
        <<<(N1 + 127) / 128, 256, 0, stream>>>(xb, hn, wfrag1, b1_r0, b1_r1, h1, N1);

    // 5-6. layer 2
    aggregate_kernel<<<(2 * N2 + 3) / 4, 256, 0, stream>>>(
        h1, row_beg + 2 * N1, row_cnt + 2 * N1, eidx, hn, 2 * N2);
    mfma_combine_kernel<false, float>
        <<<(N2 + 127) / 128, 256, 0, stream>>>(h1, hn, wfrag2, b2_r0, b2_r1, out, N2);
}

// Round 10
// 257.852 us; speedup vs baseline: 1.0734x; 1.0498x over previous
//
#include <hip/hip_runtime.h>
#include <hip/hip_bf16.h>
#include <hip/hip_fp8.h>

#define N0 100000
#define N1 50000
#define N2 20000
#define DD 128
#define E0 600000
#define E1 300000

#define NSEG_TOT (2 * N1 + 2 * N2)              // 140000 concat CSR segments
#define ETOT     (2 * E0 + 2 * E1)              // 1800000 edges

// counting-sort geometry
#define SEG_SHIFT 9                              // 512 segments per bucket
#define NBK  ((NSEG_TOT + 511) / 512)            // 274 buckets
#define CH   2048                                // edges per chunk
#define NCH  ((ETOT + CH - 1) / CH)              // 879 chunks
#define PADCAP 8192                              // eidx slots per bucket (mean 6582, +20 sigma)

#define CAST_BLOCKS 6250                         // N0*DD/8 / 256
#define PREP_BLOCKS 48                           // 2*6144/256
#define PROLOGUE_BLOCKS (CAST_BLOCKS + PREP_BLOCKS + NCH)

typedef __attribute__((ext_vector_type(8))) short short8;   // 8 bf16 (4 VGPRs)
typedef __attribute__((ext_vector_type(4))) float floatx4;  // MFMA acc
typedef __attribute__((ext_vector_type(2))) float floatx2;  // cvt_pk result

__device__ __forceinline__ void st2bf(__hip_bfloat16* p, float a, float b) {
    __hip_bfloat162 v;
    v.x = __float2bfloat16(a);
    v.y = __float2bfloat16(b);
    *(__hip_bfloat162*)p = v;
}
__device__ __forceinline__ short bf16bits(float v) {
    __hip_bfloat16 b = __float2bfloat16(v);
    return *(short*)&b;
}
__device__ __forceinline__ float bf2f(unsigned short u) {
    return __uint_as_float(((unsigned int)u) << 16);
}
__device__ __forceinline__ float4 ld4bf(const __hip_bfloat16* p) {  // 8B load
    ushort4 u = *(const ushort4*)p;
    return make_float4(bf2f(u.x), bf2f(u.y), bf2f(u.z), bf2f(u.w));
}
__device__ __forceinline__ void st4bf(__hip_bfloat16* p, float4 v) { // 8B store
    short vs[4];
    vs[0] = bf16bits(v.x); vs[1] = bf16bits(v.y);
    vs[2] = bf16bits(v.z); vs[3] = bf16bits(v.w);
    *(int2*)p = *(int2*)vs;
}

// --- HW fp8 (OCP e4m3) conversion: v_cvt_pk_fp8_f32 / v_cvt_pk_f32_fp8 ---
__device__ __forceinline__ unsigned f8enc4(float x, float y, float z, float w) {
    int v = 0;
    v = __builtin_amdgcn_cvt_pk_fp8_f32(x, y, v, false);   // bytes 0,1
    v = __builtin_amdgcn_cvt_pk_fp8_f32(z, w, v, true);    // bytes 2,3
    return (unsigned)v;
}
// decode 8 fp8 and accumulate with a mask-scale (fma keeps loads hoistable)
__device__ __forceinline__ void f8acc8m(unsigned lo, unsigned hi, float m, float* acc) {
    floatx2 p0 = __builtin_amdgcn_cvt_pk_f32_fp8((int)lo, false);
    floatx2 p1 = __builtin_amdgcn_cvt_pk_f32_fp8((int)lo, true);
    floatx2 p2 = __builtin_amdgcn_cvt_pk_f32_fp8((int)hi, false);
    floatx2 p3 = __builtin_amdgcn_cvt_pk_f32_fp8((int)hi, true);
    acc[0] = fmaf(m, p0[0], acc[0]); acc[1] = fmaf(m, p0[1], acc[1]);
    acc[2] = fmaf(m, p1[0], acc[2]); acc[3] = fmaf(m, p1[1], acc[3]);
    acc[4] = fmaf(m, p2[0], acc[4]); acc[5] = fmaf(m, p2[1], acc[5]);
    acc[6] = fmaf(m, p3[0], acc[6]); acc[7] = fmaf(m, p3[1], acc[7]);
}

// inclusive Hillis-Steele scan over 256 threads; every thread must call.
__device__ __forceinline__ int scan256(int s, int* sh, int t) {
    sh[t] = s;
    __syncthreads();
    for (int off = 1; off < 256; off <<= 1) {
        int tmp = (t >= off) ? sh[t - off] : 0;
        __syncthreads();
        sh[t] += tmp;
        __syncthreads();
    }
    return sh[t];
}

// Edge mapping for the concatenated CSR (4 edge lists)
__device__ __forceinline__ int2 edge_seg_src(int e,
    const int* s0, const int* d0, const int* s1, const int* d1,
    const int* s2, const int* d2, const int* s3, const int* d3)
{
    if (e < E0)               return make_int2(s0[e],            d0[e]);
    if (e < 2 * E0)           return make_int2(s1[e - E0],       N1 + d1[e - E0]);
    if (e < 2 * E0 + E1)      return make_int2(s2[e - 2 * E0],   2 * N1 + d2[e - 2 * E0]);
    int ee = e - 2 * E0 - E1;
    return make_int2(s3[ee], 2 * N1 + N2 + d3[ee]);
}

// ---------------------------------------------------------------------------
// Prologue: [cast | weight-prep | chunk-local bucket sort], by blockIdx range.
// ---------------------------------------------------------------------------
__global__ __launch_bounds__(256) void prologue_kernel(
    const float* __restrict__ x, __hip_bfloat16* __restrict__ xb,
    unsigned char* __restrict__ xf8,
    const int* __restrict__ s0a, const int* __restrict__ d0a,
    const int* __restrict__ s0b, const int* __restrict__ d0b,
    const int* __restrict__ s1a, const int* __restrict__ d1a,
    const int* __restrict__ s1b, const int* __restrict__ d1b,
    int* __restrict__ cntmat, int* __restrict__ ofsmat,
    unsigned* __restrict__ chunkbuf,
    const float* __restrict__ Ws1a, const float* __restrict__ Ws1b,
    const float* __restrict__ Wn1a, const float* __restrict__ Wn1b,
    const float* __restrict__ Ws2a, const float* __restrict__ Ws2b,
    const float* __restrict__ Wn2a, const float* __restrict__ Wn2b,
    short* __restrict__ wfrag1, short* __restrict__ wfrag2)
{
    __shared__ int hist[512];
    __shared__ int ofs[512];
    __shared__ int sh[256];
    __shared__ unsigned rec[CH];
    const int bid = blockIdx.x;
    const int t = threadIdx.x;

    if (bid < CAST_BLOCKS) {
        int i = bid * 256 + t;                          // 8-elem group, < 1.6M exactly
        const float4* xp = (const float4*)x + (size_t)i * 2;
        float4 a = xp[0], b = xp[1];
        __hip_bfloat16* pb = xb + (size_t)i * 8;
        st2bf(pb + 0, a.x, a.y); st2bf(pb + 2, a.z, a.w);
        st2bf(pb + 4, b.x, b.y); st2bf(pb + 6, b.z, b.w);
        uint2 w8;
        w8.x = f8enc4(a.x, a.y, a.z, a.w);
        w8.y = f8enc4(b.x, b.y, b.z, b.w);
        *(uint2*)(xf8 + (size_t)i * 8) = w8;
    } else if (bid < CAST_BLOCKS + PREP_BLOCKS) {
        int p = (bid - CAST_BLOCKS) * 256 + t;          // < 12288
        int layer = p >= 6144;
        int q = p - layer * 6144;
        int lane = q & 63;
        int mt = (q >> 6) & 7;
        int kc = q >> 9;
        int n = mt * 16 + (lane & 15);
        int k0 = kc * 32 + ((lane >> 4) << 3);
        const float* Wsa = layer ? Ws2a : Ws1a;
        const float* Wsb = layer ? Ws2b : Ws1b;
        const float* Wna = layer ? Wn2a : Wn1a;
        const float* Wnb = layer ? Wn2b : Wn1b;
        short* wf = layer ? wfrag2 : wfrag1;
        short vals[8];
#pragma unroll
        for (int j = 0; j < 8; j++) {
            int k = k0 + j;
            float w;
            if (k < 128)      w = Wsa[k * DD + n] + Wsb[k * DD + n];
            else if (k < 256) w = Wna[(k - 128) * DD + n];
            else              w = Wnb[(k - 256) * DD + n];
            vals[j] = bf16bits(w);
        }
        *(short8*)(wf + (size_t)q * 8) = *(short8*)vals;
    } else {
        const int chunk = bid - CAST_BLOCKS - PREP_BLOCKS;
        const int ebase = chunk * CH;
        const int ecount = (ETOT - ebase < CH) ? (ETOT - ebase) : CH;

        hist[t] = 0; hist[t + 256] = 0;
        __syncthreads();

        int2 myrec[CH / 256];
#pragma unroll
        for (int it = 0; it < CH / 256; it++) {
            int e = ebase + it * 256 + t;
            int2 r = make_int2(0, -1);
            if (e < ETOT) {
                r = edge_seg_src(e, s0a, d0a, s0b, d0b, s1a, d1a, s1b, d1b);
                atomicAdd(&hist[r.y >> SEG_SHIFT], 1);   // LDS atomic
            }
            myrec[it] = r;
        }
        __syncthreads();

        // exclusive scan over 512 bucket slots (2/thread)
        const int l0 = 2 * t, l1 = 2 * t + 1;
        int c0 = hist[l0], c1 = hist[l1];
        int s = c0 + c1;
        int incl = scan256(s, sh, t);
        int ex = incl - s;
        ofs[l0] = ex;
        ofs[l1] = ex + c0;
        __syncthreads();

        // write per-chunk counts and offsets (before cursors mutate ofs)
        for (int g = t; g < NBK; g += 256) {
            cntmat[(size_t)g * NCH + chunk] = hist[g];
            ofsmat[(size_t)g * NCH + chunk] = ofs[g];
        }
        __syncthreads();

        // scatter packed records into bucket order in LDS (ofs now cursors)
#pragma unroll
        for (int it = 0; it < CH / 256; it++) {
            int2 r = myrec[it];
            if (r.y >= 0) {
                int rk = atomicAdd(&ofs[r.y >> SEG_SHIFT], 1);  // LDS atomic
                rec[rk] = (unsigned)r.x | ((unsigned)(r.y & 511) << 17);
            }
        }
        __syncthreads();

        for (int i = t; i < ecount; i += 256)
            chunkbuf[ebase + i] = rec[i];
    }
}

// ---------------------------------------------------------------------------
// Finalize: block g scans its OWN cntmat row, gathers chunk slices into LDS,
// LDS hist+scan -> row_beg/cnt, scatters srcs into padded eidx region.
// ---------------------------------------------------------------------------
__global__ __launch_bounds__(256) void csr_finalize_kernel(
    const unsigned* __restrict__ chunkbuf,
    const int* __restrict__ cntmat, const int* __restrict__ ofsmat,
    int* __restrict__ row_beg, int* __restrict__ row_cnt,
    int* __restrict__ eidx)
{
    __shared__ int sh[256];
    __shared__ int preL[NCH];
    __shared__ int lenL[NCH];
    __shared__ int cnt[512];
    __shared__ int excl[512];
    __shared__ unsigned rec[PADCAP];
    const int t = threadIdx.x;
    const int g = blockIdx.x;
    const int l0 = 2 * t, l1 = 2 * t + 1;

    // 1. scan own cntmat row -> preL (exclusive), lenL
    int v[4]; int s = 0;
#pragma unroll
    for (int i = 0; i < 4; i++) {
        int idx = t * 4 + i;
        v[i] = (idx < NCH) ? cntmat[(size_t)g * NCH + idx] : 0;
        s += v[i];
    }
    int incl = scan256(s, sh, t);
    int ex = incl - s;
#pragma unroll
    for (int i = 0; i < 4; i++) {
        int idx = t * 4 + i;
        if (idx < NCH) { preL[idx] = ex; lenL[idx] = v[i]; }
        ex += v[i];
    }
    int Eloc = sh[255];
    if (Eloc > PADCAP) Eloc = PADCAP;     // statistically impossible; safety clamp
    cnt[l0] = 0; cnt[l1] = 0;
    __syncthreads();

    // 2. gather slices into rec at scan positions (no atomics)
    for (int c = t; c < NCH; c += 256) {
        int len = lenL[c];
        int dst = preL[c];
        int off = ofsmat[(size_t)g * NCH + c];
        const unsigned* src = chunkbuf + (size_t)c * CH + off;
        for (int i = 0; i < len; i++) rec[dst + i] = src[i];
    }
    __syncthreads();

    // 3. per-segment hist
    for (int i = t; i < Eloc; i += 256)
        atomicAdd(&cnt[rec[i] >> 17], 1);                 // LDS atomic
    __syncthreads();

    // 4. scan 512 segment counts -> excl
    int c0 = cnt[l0], c1 = cnt[l1];
    int ssum = c0 + c1;
    int inc2 = scan256(ssum, sh, t);
    int ex2 = inc2 - ssum;
    excl[l0] = ex2;
    excl[l1] = ex2 + c0;
    __syncthreads();

    // 5. write row_beg / row_cnt, then reset cnt as cursors
    const int segbase = g << SEG_SHIFT;
    const int base = g * PADCAP;
    int nloc = NSEG_TOT - segbase;
    if (nloc > 512) nloc = 512;
    for (int l = t; l < nloc; l += 256) {
        row_beg[segbase + l] = base + excl[l];
        row_cnt[segbase + l] = cnt[l];
    }
    __syncthreads();
    cnt[l0] = 0; cnt[l1] = 0;
    __syncthreads();

    // 6. scatter srcs into padded eidx region
    for (int i = t; i < Eloc; i += 256) {
        unsigned r = rec[i];
        int l = r >> 17;
        int pos = atomicAdd(&cnt[l], 1);
        eidx[base + excl[l] + pos] = (int)(r & 0x1FFFF);
    }
}

// ---------------------------------------------------------------------------
// Layer-1 aggregation (fp8 table), quad-per-segment: 16 lanes own a whole
// segment (row = 16 lanes x 8 B), 4 segments per wave. One eidx load per
// 16-row chunk; ALL row loads issued in 8-deep batches (32 in flight/wave);
// NO cross-lane reduce (lane owns 8 cols of the segment sum); coalesced
// 16-B store. Invalid rows -> index 0 + mask-fma (no garbage addresses).
// ---------------------------------------------------------------------------
__global__ __launch_bounds__(256) void aggregate_fp8_kernel(
    const unsigned char* __restrict__ xf8,
    const int* __restrict__ row_beg, const int* __restrict__ row_cnt,
    const int* __restrict__ eidx,
    __hip_bfloat16* __restrict__ hn,
    int nseg)                                    // must be multiple of 4
{
    const int wv = (blockIdx.x * 256 + threadIdx.x) >> 6;
    const int lane = threadIdx.x & 63;
    const int l16 = lane & 15;
    const int seg = wv * 4 + (lane >> 4);
    if (seg >= nseg) return;

    const int beg = row_beg[seg];                // lane-uniform within quad
    const int cnt = row_cnt[seg];

    // wave-uniform trip count = max cnt over the 4 quads
    int mc = cnt;
    mc = max(mc, __shfl_xor(mc, 16));
    mc = max(mc, __shfl_xor(mc, 32));
    mc = __builtin_amdgcn_readfirstlane(mc);

    float acc[8];
#pragma unroll
    for (int j = 0; j < 8; j++) acc[j] = 0.f;

    for (int kb = 0; kb < mc; kb += 16) {
        int ii = kb + l16;
        int safe = (cnt > 0) ? (ii < cnt ? ii : cnt - 1) : 0;
        int myidx = eidx[beg + safe];            // 16 indices per quad
#pragma unroll
        for (int h = 0; h < 2; h++) {
            int rb = kb + h * 8;
            if (rb >= mc) break;                 // wave-uniform
            uint2 vv[8];
#pragma unroll
            for (int j = 0; j < 8; j++) {
                int ri = __shfl(myidx, (lane & 48) | (h * 8 + j));
                ri = (rb + j < cnt) ? ri : 0;    // sanitize: garbage never addresses
                vv[j] = *(const uint2*)(xf8 + (size_t)ri * DD + l16 * 8);
            }
#pragma unroll
            for (int j = 0; j < 8; j++) {
                float m = (rb + j < cnt) ? 1.f : 0.f;
                f8acc8m(vv[j].x, vv[j].y, m, acc);
            }
        }
    }

    const float inv = 1.f / (float)(cnt > 1 ? cnt : 1);
    short vs[8];
#pragma unroll
    for (int j = 0; j < 8; j++) vs[j] = bf16bits(acc[j] * inv);
    *(int4*)(hn + (size_t)seg * DD + l16 * 8) = *(int4*)vs;
}

// ---------------------------------------------------------------------------
// Layer-2 aggregation (bf16 table), quad-per-segment: row = 16 lanes x 16 B
// (256-B bf16 row), 4 segments per wave, same scheme as layer 1.
// ---------------------------------------------------------------------------
__global__ __launch_bounds__(256) void aggregate_kernel(
    const __hip_bfloat16* __restrict__ xb,
    const int* __restrict__ row_beg, const int* __restrict__ row_cnt,
    const int* __restrict__ eidx,
    __hip_bfloat16* __restrict__ hn,
    int nseg)                                    // must be multiple of 4
{
    const int wv = (blockIdx.x * 256 + threadIdx.x) >> 6;
    const int lane = threadIdx.x & 63;
    const int l16 = lane & 15;
    const int seg = wv * 4 + (lane >> 4);
    if (seg >= nseg) return;

    const int beg = row_beg[seg];
    const int cnt = row_cnt[seg];

    int mc = cnt;
    mc = max(mc, __shfl_xor(mc, 16));
    mc = max(mc, __shfl_xor(mc, 32));
    mc = __builtin_amdgcn_readfirstlane(mc);

    float acc[8];
#pragma unroll
    for (int j = 0; j < 8; j++) acc[j] = 0.f;

    for (int kb = 0; kb < mc; kb += 16) {
        int ii = kb + l16;
        int safe = (cnt > 0) ? (ii < cnt ? ii : cnt - 1) : 0;
        int myidx = eidx[beg + safe];
#pragma unroll
        for (int h = 0; h < 2; h++) {
            int rb = kb + h * 8;
            if (rb >= mc) break;                 // wave-uniform
            ushort4 va[8], vb[8];
#pragma unroll
            for (int j = 0; j < 8; j++) {
                int ri = __shfl(myidx, (lane & 48) | (h * 8 + j));
                ri = (rb + j < cnt) ? ri : 0;
                const __hip_bfloat16* p = xb + (long)ri * DD + l16 * 8;
                va[j] = *(const ushort4*)p;      // cols [l16*8, l16*8+4)
                vb[j] = *(const ushort4*)(p + 4);
            }
#pragma unroll
            for (int j = 0; j < 8; j++) {
                float m = (rb + j < cnt) ? 1.f : 0.f;
                acc[0] = fmaf(m, bf2f(va[j].x), acc[0]);
                acc[1] = fmaf(m, bf2f(va[j].y), acc[1]);
                acc[2] = fmaf(m, bf2f(va[j].z), acc[2]);
                acc[3] = fmaf(m, bf2f(va[j].w), acc[3]);
                acc[4] = fmaf(m, bf2f(vb[j].x), acc[4]);
                acc[5] = fmaf(m, bf2f(vb[j].y), acc[5]);
                acc[6] = fmaf(m, bf2f(vb[j].z), acc[6]);
                acc[7] = fmaf(m, bf2f(vb[j].w), acc[7]);
            }
        }
    }

    const float inv = 1.f / (float)(cnt > 1 ? cnt : 1);
    short vs[8];
#pragma unroll
    for (int j = 0; j < 8; j++) vs[j] = bf16bits(acc[j] * inv);
    *(int4*)(hn + (size_t)seg * DD + l16 * 8) = *(int4*)vs;
}

// ---------------------------------------------------------------------------
// MFMA combine: D[outcol][node] = Wc^T (A-op) x Xcat^T (B-op), K=384.
// ---------------------------------------------------------------------------
template <bool RELU, typename TOUT>
__global__ __launch_bounds__(256) void mfma_combine_kernel(
    const __hip_bfloat16* __restrict__ xself,   // [M][128] bf16
    const __hip_bfloat16* __restrict__ hn,      // [2*M][128] bf16
    const short* __restrict__ wfrag,            // 12*8*64*8 bf16 bits
    const float* __restrict__ b0, const float* __restrict__ b1,
    TOUT* __restrict__ out, int M)
{
    const int t = threadIdx.x;
    const int wave = t >> 6;
    const int lane = t & 63;
    const int nsub = lane & 15;
    const int quad = lane >> 4;
    const int base = blockIdx.x * 128 + wave * 32;

    const int node0 = base + nsub;
    const int node1 = base + 16 + nsub;
    const long n0c = node0 < M ? node0 : M - 1;
    const long n1c = node1 < M ? node1 : M - 1;

    floatx4 acc[2][8];
#pragma unroll
    for (int nt = 0; nt < 2; nt++)
#pragma unroll
        for (int mt = 0; mt < 8; mt++) acc[nt][mt] = (floatx4){0.f, 0.f, 0.f, 0.f};

    for (int kc = 0; kc < 12; kc++) {
        const __hip_bfloat16* src;
        long r0, r1;
        int koff;
        if (kc < 4)      { src = xself; koff = kc * 32;       r0 = n0c;     r1 = n1c; }
        else if (kc < 8) { src = hn;    koff = (kc - 4) * 32; r0 = n0c;     r1 = n1c; }
        else             { src = hn;    koff = (kc - 8) * 32; r0 = M + n0c; r1 = M + n1c; }

        short8 bf0 = *(const short8*)(src + r0 * DD + koff + quad * 8);
        short8 bf1 = *(const short8*)(src + r1 * DD + koff + quad * 8);
        const short* wbase = wfrag + ((size_t)(kc * 8) * 64 + lane) * 8;
#pragma unroll
        for (int mt = 0; mt < 8; mt++) {
            short8 af = *(const short8*)(wbase + (size_t)mt * 64 * 8);
            acc[0][mt] = __builtin_amdgcn_mfma_f32_16x16x32_bf16(af, bf0, acc[0][mt], 0, 0, 0);
            acc[1][mt] = __builtin_amdgcn_mfma_f32_16x16x32_bf16(af, bf1, acc[1][mt], 0, 0, 0);
        }
    }

#pragma unroll
    for (int nt = 0; nt < 2; nt++) {
        int node = (nt == 0) ? node0 : node1;
        if (node >= M) continue;
#pragma unroll
        for (int mt = 0; mt < 8; mt++) {
            int c0 = mt * 16 + quad * 4;
            float4 bb0 = *(const float4*)(b0 + c0);
            float4 bb1 = *(const float4*)(b1 + c0);
            float v0 = acc[nt][mt][0] + bb0.x + bb1.x;
            float v1 = acc[nt][mt][1] + bb0.y + bb1.y;
            float v2 = acc[nt][mt][2] + bb0.z + bb1.z;
            float v3 = acc[nt][mt][3] + bb0.w + bb1.w;
            if (RELU) {
                v0 = v0 > 0.f ? v0 : 0.f;
                v1 = v1 > 0.f ? v1 : 0.f;
                v2 = v2 > 0.f ? v2 : 0.f;
                v3 = v3 > 0.f ? v3 : 0.f;
            }
            TOUT* p = out + (long)node * DD + c0;
            if constexpr (sizeof(TOUT) == 4) {
                *(float4*)p = make_float4(v0, v1, v2, v3);
            } else {
                short vs[4];
                vs[0] = bf16bits(v0); vs[1] = bf16bits(v1);
                vs[2] = bf16bits(v2); vs[3] = bf16bits(v3);
                *(int2*)p = *(int2*)vs;
            }
        }
    }
}

// ---------------------------------------------------------------------------

extern "C" void kernel_launch(void* const* d_in, const int* in_sizes, int n_in,
                              void* d_out, int out_size, void* d_ws, size_t ws_size,
                              hipStream_t stream)
{
    const float* x = (const float*)d_in[0];
    const int* e0_src_r0 = (const int*)d_in[1];
    const int* e0_dst_r0 = (const int*)d_in[2];
    const int* e0_src_r1 = (const int*)d_in[3];
    const int* e0_dst_r1 = (const int*)d_in[4];
    const int* e1_src_r0 = (const int*)d_in[5];
    const int* e1_dst_r0 = (const int*)d_in[6];
    const int* e1_src_r1 = (const int*)d_in[7];
    const int* e1_dst_r1 = (const int*)d_in[8];
    const float* Ws1_r0 = (const float*)d_in[9];
    const float* Wn1_r0 = (const float*)d_in[10];
    const float* Ws1_r1 = (const float*)d_in[11];
    const float* Wn1_r1 = (const float*)d_in[12];
    const float* Ws2_r0 = (const float*)d_in[13];
    const float* Wn2_r0 = (const float*)d_in[14];
    const float* Ws2_r1 = (const float*)d_in[15];
    const float* Wn2_r1 = (const float*)d_in[16];
    const float* b1_r0 = (const float*)d_in[17];
    const float* b1_r1 = (const float*)d_in[18];
    const float* b2_r0 = (const float*)d_in[19];
    const float* b2_r1 = (const float*)d_in[20];
    float* out = (float*)d_out;

    __hip_bfloat16* xb = (__hip_bfloat16*)d_ws;
    __hip_bfloat16* h1 = xb;
    unsigned char* xf8 = (unsigned char*)(xb + (size_t)N0 * DD);
    __hip_bfloat16* hn = (__hip_bfloat16*)(xf8 + (size_t)N0 * DD);
    unsigned* chunkbuf = (unsigned*)hn;
    int* eidx     = (int*)(hn + (size_t)2 * N1 * DD);
    int* row_beg  = eidx + NBK * PADCAP;
    int* row_cnt  = row_beg + NSEG_TOT;
    int* cntmat   = row_cnt + NSEG_TOT;
    int* ofsmat   = cntmat + NBK * NCH;
    short* wfrag1 = (short*)(ofsmat + NBK * NCH);
    short* wfrag2 = wfrag1 + 12 * 8 * 64 * 8;

    // 1. prologue: cast (bf16 + fp8) + weight-prep + chunk-local bucket sort
    prologue_kernel<<<PROLOGUE_BLOCKS, 256, 0, stream>>>(
        x, xb, xf8,
        e0_src_r0, e0_dst_r0, e0_src_r1, e0_dst_r1,
        e1_src_r0, e1_dst_r0, e1_src_r1, e1_dst_r1,
        cntmat, ofsmat, chunkbuf,
        Ws1_r0, Ws1_r1, Wn1_r0, Wn1_r1,
        Ws2_r0, Ws2_r1, Wn2_r0, Wn2_r1,
        wfrag1, wfrag2);

    // 2. per-bucket finalize (own-row scan -> gather -> row_beg/cnt + eidx)
    csr_finalize_kernel<<<NBK, 256, 0, stream>>>(
        chunkbuf, cntmat, ofsmat, row_beg, row_cnt, eidx);

    // 3-4. layer 1 (quad-per-segment: 4 segments/wave, 16 waves/block)
    aggregate_fp8_kernel<<<(2 * N1) / 16, 256, 0, stream>>>(
        xf8, row_beg, row_cnt, eidx, hn, 2 * N1);
    mfma_combine_kernel<true, __hip_bfloat16>
        <<<(N1 + 127) / 128, 256, 0, stream>>>(xb, hn, wfrag1, b1_r0, b1_r1, h1, N1);

    // 5-6. layer 2 (quad-per-segment)
    aggregate_kernel<<<(2 * N2) / 16, 256, 0, stream>>>(
        h1, row_beg + 2 * N1, row_cnt + 2 * N1, eidx, hn, 2 * N2);
    mfma_combine_kernel<false, float>
        <<<(N2 + 127) / 128, 256, 0, stream>>>(h1, hn, wfrag2, b2_r0, b2_r1, out, N2);
}